// Round 9
// baseline (2186.381 us; speedup 1.0000x reference)
//
#include <hip/hip_runtime.h>

// FixedPtSQP: 1024 independent SQP solves, N=64, M_IN=128 (G=[I;-I]), M_EQ=1 (A=1^T).
// R8: TWO waves per problem (128-thread block) -> 2048 waves -> 2 waves/SIMD.
// The grid previously pinned occupancy at 1 wave/SIMD (1024 problems x 1 wave);
// true VALU busy was only ~25% (gfx94x-formula VALUBusy double-counts on CDNA4),
// i.e. stall-dominated with nothing to hide latency. Split: wave w owns columns
// j == w (mod 2); lane i owns row i. Per-row IPM state is DUPLICATED in both
// waves (bitwise-identical, no comms); only the O(N^3) trailing update splits.
// Column-k owner broadcasts from registers via readlane; the other wave reads
// the column from colbuf (early-written one step before, latency hidden).
// One __syncthreads per k; double-buffered colbuf makes it safe.

#define LS 65   // Lmat row stride: conflict-free by row and by column

typedef float v2f __attribute__((ext_vector_type(2)));

__device__ __forceinline__ float frcp(float x) { return __builtin_amdgcn_rcpf(x); }
__device__ __forceinline__ float rdl(float v, int lane) {
  return __int_as_float(__builtin_amdgcn_readlane(__float_as_int(v), lane));
}

__device__ __forceinline__ float wave_sum(float v) {
#pragma unroll
  for (int o = 32; o > 0; o >>= 1) v += __shfl_xor(v, o, 64);
  return v;
}
__device__ __forceinline__ float wave_min(float v) {
#pragma unroll
  for (int o = 32; o > 0; o >>= 1) v = fminf(v, __shfl_xor(v, o, 64));
  return v;
}

// Column j (own parity) -> packed slot j>>1 -> v2f element
#define HR(j) (hreg[(j) >> 2][((j) >> 1) & 1])

__global__ __launch_bounds__(128, 1) void sqp_solve_kernel(
    const float* __restrict__ C, const float* __restrict__ Q,
    float* __restrict__ out) {
  const int b = blockIdx.x;
  const int tid = threadIdx.x;
  const int i = tid & 63;    // row index (same in both waves)
  const int wid = tid >> 6;  // wave id == column parity owned

  __shared__ __align__(16) float Qp[2][64][36];   // parity-packed Q: Qp[w][i][jj]=Q[i][2jj+w]
  __shared__ __align__(16) float Lmat[64 * LS];   // unit-lower L (transpose access in bwd)
  __shared__ __align__(16) float colbuf[2][64];   // active column, double-buffered
  __shared__ __align__(16) float xpbuf[2][32];    // parity-packed x
  __shared__ __align__(16) float pbuf[2][64];     // p partial exchange

  // Stage own-parity plane of Q (each wave reads the full row, keeps its half)
#pragma unroll
  for (int t = 0; t < 16; ++t) {
    const float4 q = *reinterpret_cast<const float4*>(&Q[i * 64 + 4 * t]);
    Qp[wid][i][2 * t]     = wid ? q.y : q.x;
    Qp[wid][i][2 * t + 1] = wid ? q.w : q.z;
  }
  const float ci = C[b * 64 + i];
  __syncthreads();

  float x = 0.5f, d = 0.0f;

#pragma unroll 1
  for (int sqp = 0; sqp < 6; ++sqp) {   // MAX_ITER1 + MAX_ITER2, ALPHA=1
    // p = Q0 x - c : parity-split matvec, partials exchanged via LDS
    if (wid == 0) xpbuf[i & 1][i >> 1] = x;   // x duplicated per lane; wave 0 packs it
    __syncthreads();
    float pp = 0.f;
#pragma unroll
    for (int t = 0; t < 8; ++t) {
      const float4 qv = *reinterpret_cast<const float4*>(&Qp[wid][i][4 * t]);
      const float4 xv = *reinterpret_cast<const float4*>(&xpbuf[wid][4 * t]);
      pp = fmaf(qv.x, xv.x, pp); pp = fmaf(qv.y, xv.y, pp);
      pp = fmaf(qv.z, xv.z, pp); pp = fmaf(qv.w, xv.w, pp);
    }
    pbuf[wid][i] = pp;
    const float h1 = 1.0f - x;
    const float h2v = x;
    const float beq = 1.0f - wave_sum(x);
    __syncthreads();
    const float p = pbuf[0][i] + pbuf[1][i] - ci;

    // QP state: duplicated bitwise-identically in both waves
    float z = 0.f, s1 = 1.f, s2 = 1.f, l1 = 1.f, l2 = 1.f, nu = 0.f;
    float Qz = 0.f, Sz = 0.f;

#pragma unroll 1
    for (int it = 0; it < 15; ++it) {   // NEWTON_ITERS
      const float mu = 0.1f * wave_sum(fmaf(s1, l1, s2 * l2)) * (1.0f / 128.0f);

      // Fresh own-parity H row (raw Q; dd enters only via the pivot)
      v2f hreg[16];
#pragma unroll
      for (int t = 0; t < 8; ++t) {
        const float4 qv = *reinterpret_cast<const float4*>(&Qp[wid][i][4 * t]);
        hreg[2 * t]     = (v2f){qv.x, qv.y};
        hreg[2 * t + 1] = (v2f){qv.z, qv.w};
      }

      const float rs1 = frcp(s1), rs2 = frcp(s2);
      const float r_dual = Qz + p + (l1 - l2) + nu;
      const float rp1 = z + s1 - h1;
      const float rp2 = -z + s2 - h2v;
      const float r_peq = Sz - beq;
      const float rc1 = fmaf(l1, s1, -mu);
      const float rc2 = fmaf(l2, s2, -mu);
      const float dd = fmaf(l1, rs1, l2 * rs2);   // per-lane (row i)
      const float w1 = (l1 * rp1 - rc1) * rs1;
      const float w2 = (l2 * rp2 - rc2) * rs2;
      const float rhs = -(r_dual + w1 - w2);

      // Seed column 0 (parity 0 -> wave 0's slot 0)
      if (wid == 0) colbuf[0][i] = hreg[0].x;
      float a1 = rhs, a2 = 1.0f, myrd = 0.0f;
      __syncthreads();

      // Interleaved-ownership LDL^T with fused forward solve.
#pragma unroll
      for (int k = 0; k < 64; ++k) {
        const float* cc = colbuf[k & 1];
        float lik;
        if (wid == (k & 1)) {
          // OWNER of column k: data in registers, broadcast via readlane
          const float hk = HR(k);
          const float piv = rdl(hk, k) + rdl(dd, k);
          const float rd = frcp(piv);
          lik = hk * rd;
          myrd = (i == k) ? rd : myrd;
          // trailing own-parity j = k+2, k+4, ...
#pragma unroll
          for (int j = k + 2; j < 64; j += 2) {
            const float w = rdl(hk, j);
            HR(j) = fmaf(-lik, w, HR(j));
          }
        } else {
          // NON-OWNER: column k from colbuf (written at step k-1)
          const float piv = cc[k] + rdl(dd, k);   // same bits as owner's piv
          const float rd = frcp(piv);
          lik = cc[i] * rd;
          myrd = (i == k) ? rd : myrd;
          if (k < 63) {
            // early write of column k+1 (my parity): next step's colbuf
            const float wn = fmaf(-lik, cc[k + 1], HR(k + 1));
            HR(k + 1) = wn;
            colbuf[(k + 1) & 1][i] = wn;
          }
          // trailing own-parity j = k+3, k+5, ...
#pragma unroll
          for (int j = k + 3; j < 64; j += 2) {
            HR(j) = fmaf(-lik, cc[j], HR(j));
          }
        }
        // fused forward solve (duplicated; lanes i<=k frozen)
        const float t1 = rdl(a1, k);
        const float t2 = rdl(a2, k);
        const float likm = (i > k) ? lik : 0.0f;
        a1 = fmaf(-likm, t1, a1);
        a2 = fmaf(-likm, t2, a2);
        if (wid == 0 && k < 63) Lmat[i * LS + k] = lik;   // both waves have lik; one writes
        __syncthreads();
      }

      // D-scale then backward solve L^T u = a (duplicated in both waves)
      a1 *= myrd;
      a2 *= myrd;
#pragma unroll
      for (int k = 63; k >= 1; --k) {
        const float t1 = rdl(a1, k);
        const float t2 = rdl(a2, k);
        const float lki = (i < k) ? Lmat[k * LS + i] : 0.0f;
        a1 = fmaf(-lki, t1, a1);
        a2 = fmaf(-lki, t2, a2);
      }
      // a1 = u1, a2 = u2. Dual reduction (interleaved for ILP):
      float su1 = a1, su2 = a2;
#pragma unroll
      for (int o = 32; o > 0; o >>= 1) {
        su1 += __shfl_xor(su1, o, 64);
        su2 += __shfl_xor(su2, o, 64);
      }
      const float dnu = (su1 + r_peq) * frcp(su2);
      const float dz = fmaf(-dnu, a2, a1);

      const float dl1 = (l1 * (rp1 + dz) - rc1) * rs1;
      const float dl2 = (l2 * (rp2 - dz) - rc2) * rs2;
      const float ds1 = -rp1 - dz;
      const float ds2 = -rp2 + dz;

      const float c1m = (dl1 < 0.0f) ? (-l1 * frcp(dl1)) : 1.0f;
      const float c2m = (dl2 < 0.0f) ? (-l2 * frcp(dl2)) : 1.0f;
      const float c3m = (ds1 < 0.0f) ? (-s1 * frcp(ds1)) : 1.0f;
      const float c4m = (ds2 < 0.0f) ? (-s2 * frcp(ds2)) : 1.0f;
      const float am = wave_min(fminf(fminf(c1m, c2m), fminf(c3m, c4m)));
      const float a = 0.99f * fminf(1.0f, am);

      // Incremental trackers: H u = r  =>  Q u = r - dd*u
      const float Qdz = (rhs - dd * a1) - dnu * (1.0f - dd * a2);
      Qz = fmaf(a, Qdz, Qz);
      Sz = fmaf(a, su1 - dnu * su2, Sz);

      z = fmaf(a, dz, z);
      s1 = fmaf(a, ds1, s1);
      s2 = fmaf(a, ds2, s2);
      l1 = fmaf(a, dl1, l1);
      l2 = fmaf(a, dl2, l2);
      nu = fmaf(a, dnu, nu);
    }

    x += z;   // ALPHA=1; lam carried in reference but never read
    d = z;
  }

  if (wid == 0) out[b * 64 + i] = x + d;   // reference returns x + d
}

extern "C" void kernel_launch(void* const* d_in, const int* in_sizes, int n_in,
                              void* d_out, int out_size, void* d_ws, size_t ws_size,
                              hipStream_t stream) {
  const float* c = (const float*)d_in[0];   // (B, 64) f32
  const float* Q = (const float*)d_in[1];   // (64, 64) f32
  float* out = (float*)d_out;               // (B, 64) f32
  const int B = in_sizes[0] / 64;
  hipLaunchKernelGGL(sqp_solve_kernel, dim3(B), dim3(128), 0, stream, c, Q, out);
}